// Round 1
// 73.751 us; speedup vs baseline: 1.0086x; 1.0086x over previous
//
#include <hip/hip_runtime.h>

// MoE_v2: 128 rows x 4 Gaussians on a 256x256 grid.
// out[n, h] = clamp( (sum_k e_k * w_k) / max(sum_k e_k, 1e-7), 0, 1 )
//   e_k = exp(-0.5 * (u0^2 + u1^2)),  u0 = dx*S00 + dy*S10, u1 = dy*S11 (tril)
//   dx = x - mu_x[k], dy = y - mu_y[k],  x = a/255, y = b/255, h = a*256 + b
//
// Param row layout (28 floats): [mu_x(4), mu_y(4), w(4), Sig(4x2x2 row-major)]
//   S00[k]=p[12+4k], S10[k]=p[14+4k], S11[k]=p[15+4k]  (S01 zeroed by tril)
//
// Change vs v1 (74.4 us): each thread now covers TWO x-columns (a and a+128)
// at the same 4 consecutive y's (8 pixels/thread, two dense float4 stores).
// u1 = fma(y, s11c, B0) and u1^2 depend only on (y,k,n) -> shared between the
// two columns, cutting the inner body from 6 VALU/pixel to 5 VALU/pixel.
// Wave count halves (32768 -> 16384), so the per-thread prologue (param
// loads + per-k constant folding) amortizes over 2x the pixels.
// exp(-0.5*s) folded into exp2 via pre-scaling S by c = sqrt(0.5*log2(e)).

#define K 4
#define TPB 256

__global__ __launch_bounds__(TPB) void moe_splat_kernel(
    const float* __restrict__ params, float* __restrict__ out)
{
    const int n  = blockIdx.x >> 5;                        // batch row (block-uniform)
    const int t  = ((blockIdx.x & 31) << 8) | threadIdx.x; // [0, 8192) within batch
    const int a  = t >> 6;                                 // x index [0,128)
    const int b0 = (t & 63) << 2;                          // first y index (mult of 4)

    const float inv255 = 1.0f / 255.0f;
    // c = sqrt(0.5 * log2(e)) : folds exp(-0.5*s) into exp2(-(c*u)^2 terms)
    const float c  = 0.84932184f;
    const float x0 = (float)a * inv255;
    const float x1 = x0 + 128.0f * inv255;

    // Block-uniform param row -> scalar loads
    const float* __restrict__ p = params + n * 28;

    float A0[K], A1[K], B0[K], w[K], s10c[K], s11c[K];
#pragma unroll
    for (int k = 0; k < K; ++k) {
        const float mux  = p[k];
        const float muy  = p[4 + k];
        w[k]             = p[8 + k];
        const float s00c = p[12 + 4 * k] * c;
        s10c[k]          = p[14 + 4 * k] * c;
        s11c[k]          = p[15 + 4 * k] * c;
        const float base = -muy * s10c[k];        // u0 = fma(y, s10c, A)
        A0[k] = fmaf(x0 - mux, s00c, base);
        A1[k] = fmaf(x1 - mux, s00c, base);
        B0[k] = -muy * s11c[k];                   // u1 = fma(y, s11c, B0)
    }

    float yv[4];
#pragma unroll
    for (int j = 0; j < 4; ++j) yv[j] = (float)(b0 + j) * inv255;

    float acc0[4] = {0.f, 0.f, 0.f, 0.f};
    float g0[4]   = {0.f, 0.f, 0.f, 0.f};
    float acc1[4] = {0.f, 0.f, 0.f, 0.f};
    float g1[4]   = {0.f, 0.f, 0.f, 0.f};

#pragma unroll
    for (int k = 0; k < K; ++k) {
#pragma unroll
        for (int j = 0; j < 4; ++j) {
            const float u1  = fmaf(yv[j], s11c[k], B0[k]);   // shared: y-only
            const float u1s = u1 * u1;                       // shared: y-only
            const float ua  = fmaf(yv[j], s10c[k], A0[k]);   // column a
            const float ub  = fmaf(yv[j], s10c[k], A1[k]);   // column a+128
            const float sa  = fmaf(ua, ua, u1s);
            const float sb  = fmaf(ub, ub, u1s);
            const float ea  = __builtin_amdgcn_exp2f(-sa);   // v_exp_f32, neg mod free
            const float eb  = __builtin_amdgcn_exp2f(-sb);
            g0[j]  += ea;
            acc0[j] = fmaf(ea, w[k], acc0[j]);
            g1[j]  += eb;
            acc1[j] = fmaf(eb, w[k], acc1[j]);
        }
    }

    float4 oA, oB;
    float* ovA = &oA.x;
    float* ovB = &oB.x;
#pragma unroll
    for (int j = 0; j < 4; ++j) {
        const float ga = fmaxf(g0[j], 1e-7f);
        const float va = acc0[j] * __builtin_amdgcn_rcpf(ga);
        ovA[j] = fminf(fmaxf(va, 0.0f), 1.0f);
        const float gb = fmaxf(g1[j], 1e-7f);
        const float vb = acc1[j] * __builtin_amdgcn_rcpf(gb);
        ovB[j] = fminf(fmaxf(vb, 0.0f), 1.0f);
    }

    // Flat float4 index for column a: n*16384 + a*64 + (t&63) == n*16384 + t
    //   gid = blockIdx.x*TPB + tid = n*8192 + t  ->  idx = gid + n*8192
    // Column a+128 is +128*256 floats = +8192 float4s. Both stores are dense
    // across the wave (16 B lane stride).
    const int gid  = blockIdx.x * TPB + threadIdx.x;
    const int idx1 = gid + (n << 13);
    reinterpret_cast<float4*>(out)[idx1]        = oA;
    reinterpret_cast<float4*>(out)[idx1 + 8192] = oB;
}

extern "C" void kernel_launch(void* const* d_in, const int* in_sizes, int n_in,
                              void* d_out, int out_size, void* d_ws, size_t ws_size,
                              hipStream_t stream)
{
    // d_in[0]=height(int), d_in[1]=width(int), d_in[2]=params (B*1*28 fp32)
    const float* params = (const float*)d_in[2];
    float* out = (float*)d_out;

    const int total_threads = out_size / 8;   // 8 pixels per thread -> 1,048,576
    const int blocks = total_threads / TPB;   // 4096 (32 per batch row)
    moe_splat_kernel<<<blocks, TPB, 0, stream>>>(params, out);
}